// Round 12
// baseline (41.441 us; speedup 1.0000x reference)
//
#include <hip/hip_runtime.h>
#include <math.h>

#define NSAMP 1024
#define DIM   64
#define NLAYER 3

#define NT2  32                        // rows per block
#define JB   64                        // j per block
#define NTIL (NSAMP / NT2)             // 32 n-tiles
#define NJS  (NSAMP / JB)              // 16 j-slices
#define NBLK (NLAYER * NTIL * NJS)     // 1536 blocks (6/CU)

#define MAGIC_HI 0x5AFE600Du
typedef unsigned long long u64;
#define WS_REQ (NBLK * sizeof(u64))

// 2-instr |f-mu| accumulate (proven R11): v_sub + v_add with abs() modifier.
__device__ __forceinline__ void absacc(float& acc, float f, float m) {
    float d;
    asm("v_sub_f32 %1, %2, %3\n\t"
        "v_add_f32 %0, %0, abs(%1)"
        : "+v"(acc), "=&v"(d)
        : "v"(f), "v"(m));
}

// ---------------------------------------------------------------------------
// ONE dispatch, zero cross-block dependencies (head recomputed per block).
// Block (layer, ntile[32 rows], jsl[64 j]):
//   A: stage fs rows -> LDS (8 KB)
//   B: head for own 32 rows (1 col/thread x 8 rows; W rows reused in regs;
//      fs via wave-uniform LDS broadcast)  -> muL/ivL in LDS
//   C: pair loop, direct L1 float4 reads (no fr staging), asm inner body
//   D: proven MAGIC-slot finish (block 0 completion-poll, reduce, reset)
__global__ __launch_bounds__(256, 6) void ib_mono3(
    const float* __restrict__ fea0, const float* __restrict__ fea1,
    const float* __restrict__ fea2, const float* __restrict__ fea3,
    const float* __restrict__ W_mu, const float* __restrict__ b_mu,
    const float* __restrict__ W_var, const float* __restrict__ b_var,
    u64* __restrict__ slots, float* __restrict__ out)
{
    const int b     = blockIdx.x;           // 0..1535
    const int layer = b >> 9;               // 512 blocks per layer
    const int sub   = b & 511;
    const int ntile = sub & 31;             // 0..31
    const int jsl   = sub >> 5;             // 0..15
    const int tid   = threadIdx.x;

    const float* __restrict__ fr_p =
        (layer == 0) ? fea0 : (layer == 1) ? fea1 : fea2;   // reference
    const float* __restrict__ fs_p =
        (layer == 0) ? fea1 : (layer == 1) ? fea2 : fea3;   // student

    __shared__ float fsL[NT2][DIM];         // 8 KB
    __shared__ float muL[NT2][DIM];         // 8 KB
    __shared__ float ivL[NT2][DIM];         // 8 KB
    __shared__ float wsum[4];

    // ---------------- A: stage fs (32 rows, coalesced float4) ---------------
    {
        const float4* __restrict__ fsrc =
            (const float4*)(fs_p + ntile * NT2 * DIM);
        ((float4*)fsL)[tid]       = fsrc[tid];
        ((float4*)fsL)[tid + 256] = fsrc[tid + 256];
    }
    __syncthreads();

    // ---------------- B: head for own 32 rows -------------------------------
    {
        const int c  = tid & 63;            // owned column
        const int rb = tid >> 6;            // wave id 0..3
        const float4* __restrict__ wm =
            (const float4*)(W_mu + (layer * DIM + c) * DIM);
        const float4* __restrict__ wv =
            (const float4*)(W_var + (layer * DIM + c) * DIM);

        float am[8], av[8];
#pragma unroll
        for (int i = 0; i < 8; ++i) { am[i] = 0.f; av[i] = 0.f; }

#pragma unroll
        for (int k4 = 0; k4 < DIM / 4; ++k4) {
            const float4 wmk = wm[k4];      // W row reused across 8 fs rows
            const float4 wvk = wv[k4];
#pragma unroll
            for (int i = 0; i < 8; ++i) {
                // wave-uniform address -> LDS broadcast (conflict-free)
                const float4 f =
                    *reinterpret_cast<const float4*>(&fsL[rb + 4 * i][k4 * 4]);
                am[i] = fmaf(f.x, wmk.x, am[i]); am[i] = fmaf(f.y, wmk.y, am[i]);
                am[i] = fmaf(f.z, wmk.z, am[i]); am[i] = fmaf(f.w, wmk.w, am[i]);
                av[i] = fmaf(f.x, wvk.x, av[i]); av[i] = fmaf(f.y, wvk.y, av[i]);
                av[i] = fmaf(f.z, wvk.z, av[i]); av[i] = fmaf(f.w, wvk.w, av[i]);
            }
        }
        const float bm = b_mu[layer * DIM + c];
        const float bv = b_var[layer * DIM + c];
#pragma unroll
        for (int i = 0; i < 8; ++i) {
            const int r  = rb + 4 * i;
            const float mu = am[i] + bm;
            const float x  = av[i] + bv;
            const float sp = fmaxf(x, 0.f) + log1pf(expf(-fabsf(x)));
            muL[r][c] = mu;
            ivL[r][c] = 1.0f / (sp * 0.1f + 1e-6f);
        }
    }
    __syncthreads();

    // ---------------- C: pair loop (direct L1 reads, asm body) --------------
    const int q    = tid & 15;              // col group: d0..d0+3
    const int rg   = (tid >> 4) & 7;        // row group: 4 rows
    const int jsub = tid >> 7;              // 0/1: 32-j half
    const int d0   = q * 4;
    const int r0   = rg * 4;
    const int n0   = ntile * NT2 + r0;

    float4 mu4[4];
#pragma unroll
    for (int r = 0; r < 4; ++r)
        mu4[r] = *reinterpret_cast<const float4*>(&muL[r0 + r][d0]);

    float4 ps[4];
#pragma unroll
    for (int r = 0; r < 4; ++r) ps[r] = make_float4(0.f, 0.f, 0.f, 0.f);

    const float4* __restrict__ frj =
        (const float4*)(fr_p + (jsl * JB + jsub * 32) * DIM) + q;
#pragma unroll 4
    for (int jj = 0; jj < 32; ++jj) {
        const float4 f = frj[jj * (DIM / 4)];
#pragma unroll
        for (int r = 0; r < 4; ++r) {
            absacc(ps[r].x, f.x, mu4[r].x);
            absacc(ps[r].y, f.y, mu4[r].y);
            absacc(ps[r].z, f.z, mu4[r].z);
            absacc(ps[r].w, f.w, mu4[r].w);
        }
    }

    // ---------------- epilogue ----------------------------------------------
    const float inv_n = 1.0f / (float)NSAMP;
    float s = 0.f;
    {
        float4 iv4[4];
#pragma unroll
        for (int r = 0; r < 4; ++r)
            iv4[r] = *reinterpret_cast<const float4*>(&ivL[r0 + r][d0]);

        if (jsl == 0 && jsub == 0) {
            // positive term exactly once per (n,d)
#pragma unroll
            for (int r = 0; r < 4; ++r) {
                const float4 a = *(const float4*)(fr_p + (n0 + r) * DIM + d0);
                s += (ps[r].x * inv_n - fabsf(mu4[r].x - a.x)) * iv4[r].x;
                s += (ps[r].y * inv_n - fabsf(mu4[r].y - a.y)) * iv4[r].y;
                s += (ps[r].z * inv_n - fabsf(mu4[r].z - a.z)) * iv4[r].z;
                s += (ps[r].w * inv_n - fabsf(mu4[r].w - a.w)) * iv4[r].w;
            }
        } else {
#pragma unroll
            for (int r = 0; r < 4; ++r) {
                s += ps[r].x * inv_n * iv4[r].x;
                s += ps[r].y * inv_n * iv4[r].y;
                s += ps[r].z * inv_n * iv4[r].z;
                s += ps[r].w * inv_n * iv4[r].w;
            }
        }
    }

    // deterministic block reduction
#pragma unroll
    for (int off = 32; off > 0; off >>= 1)
        s += __shfl_down(s, off, 64);
    if ((tid & 63) == 0) wsum[tid >> 6] = s;
    __syncthreads();

    // one contention-free 8B MAGIC store per block (own slot)
    if (tid == 0) {
        const float p = wsum[0] + wsum[1] + wsum[2] + wsum[3];
        const u64 v = ((u64)MAGIC_HI << 32) | (u64)__float_as_uint(p);
        __hip_atomic_store(&slots[b], v, __ATOMIC_RELAXED,
                           __HIP_MEMORY_SCOPE_AGENT);
    }

    // block 0: completion-only wait (safe, proven), fixed-order reduce, reset
    if (b == 0) {
        __syncthreads();
        u64 v[6];
#pragma unroll
        for (int t = 0; t < 6; ++t) {
            u64* slot = &slots[tid + t * 256];
            for (;;) {
                const u64 x = __hip_atomic_load(slot, __ATOMIC_RELAXED,
                                                __HIP_MEMORY_SCOPE_AGENT);
                if ((unsigned)(x >> 32) == MAGIC_HI) { v[t] = x; break; }
                __builtin_amdgcn_s_sleep(1);
            }
        }
#pragma unroll
        for (int t = 0; t < 6; ++t)
            __hip_atomic_store(&slots[tid + t * 256], 0ull, __ATOMIC_RELAXED,
                               __HIP_MEMORY_SCOPE_AGENT);
        float s2 = 0.f;
#pragma unroll
        for (int t = 0; t < 6; ++t)
            s2 += __uint_as_float((unsigned)v[t]);
#pragma unroll
        for (int off = 32; off > 0; off >>= 1)
            s2 += __shfl_down(s2, off, 64);
        if ((tid & 63) == 0) wsum[tid >> 6] = s2;
        __syncthreads();
        if (tid == 0)
            out[0] = (wsum[0] + wsum[1] + wsum[2] + wsum[3]) * inv_n;
    }
}

// ---------------------------------------------------------------------------
// fallback path (tiny ws): fused kernel + final reduce
__global__ __launch_bounds__(256) void ib_fused(
    const float* __restrict__ fea0, const float* __restrict__ fea1,
    const float* __restrict__ fea2, const float* __restrict__ fea3,
    const float* __restrict__ W_mu, const float* __restrict__ b_mu,
    const float* __restrict__ W_var, const float* __restrict__ b_var,
    float* __restrict__ partials)
{
    const int layer = blockIdx.y;
    const float* feas[4] = {fea0, fea1, fea2, fea3};
    const float* __restrict__ fr_p = feas[layer];
    const float* __restrict__ fs_p = feas[layer + 1];

    const int tid = threadIdx.x;
    const int d   = tid & 63;
    const int nl  = tid >> 6;
    const int n   = blockIdx.x * 4 + nl;

    __shared__ float fs[4][DIM];
    __shared__ float fr[64][DIM];
    __shared__ float wsum[4];

    fs[nl][d] = fs_p[n * DIM + d];
    __syncthreads();

    const float* __restrict__ wm = W_mu + (layer * DIM + d) * DIM;
    const float* __restrict__ wv = W_var + (layer * DIM + d) * DIM;
    float am = 0.f, av = 0.f;
#pragma unroll
    for (int k = 0; k < DIM; ++k) {
        const float f = fs[nl][k];
        am = fmaf(f, wm[k], am);
        av = fmaf(f, wv[k], av);
    }
    const float mu = am + b_mu[layer * DIM + d];
    const float x  = av + b_var[layer * DIM + d];
    const float sp  = fmaxf(x, 0.f) + log1pf(expf(-fabsf(x)));
    const float var = sp * 0.1f + 1e-6f;

    float psum = 0.f;
    for (int j0 = 0; j0 < NSAMP; j0 += 64) {
        __syncthreads();
#pragma unroll
        for (int t = 0; t < 16; ++t) {
            const int l = tid + t * 256;
            fr[0][l] = fr_p[j0 * DIM + l];
        }
        __syncthreads();
#pragma unroll
        for (int j = 0; j < 64; ++j)
            psum += fabsf(fr[j][d] - mu);
    }

    const float frnd = fr_p[n * DIM + d];
    float t = (psum * (1.0f / NSAMP) - fabsf(mu - frnd)) / var;

#pragma unroll
    for (int off = 32; off > 0; off >>= 1)
        t += __shfl_down(t, off, 64);
    if ((tid & 63) == 0) wsum[tid >> 6] = t;
    __syncthreads();
    if (tid == 0)
        partials[blockIdx.y * gridDim.x + blockIdx.x] =
            wsum[0] + wsum[1] + wsum[2] + wsum[3];
}

__global__ __launch_bounds__(256) void ib_final(
    const float* __restrict__ partials, int np, float scale,
    float* __restrict__ out)
{
    const int tid = threadIdx.x;
    float s = 0.f;
    for (int i = tid; i < np; i += 256) s += partials[i];
#pragma unroll
    for (int off = 32; off > 0; off >>= 1)
        s += __shfl_down(s, off, 64);
    __shared__ float wsum[4];
    if ((tid & 63) == 0) wsum[tid >> 6] = s;
    __syncthreads();
    if (tid == 0) out[0] = (wsum[0] + wsum[1] + wsum[2] + wsum[3]) * scale;
}

// ---------------------------------------------------------------------------
extern "C" void kernel_launch(void* const* d_in, const int* in_sizes, int n_in,
                              void* d_out, int out_size, void* d_ws, size_t ws_size,
                              hipStream_t stream) {
    const float* fea0  = (const float*)d_in[0];
    const float* fea1  = (const float*)d_in[1];
    const float* fea2  = (const float*)d_in[2];
    const float* fea3  = (const float*)d_in[3];
    const float* W_mu  = (const float*)d_in[4];
    const float* b_mu  = (const float*)d_in[5];
    const float* W_var = (const float*)d_in[6];
    const float* b_var = (const float*)d_in[7];
    float* out = (float*)d_out;

    if (ws_size >= WS_REQ) {
        ib_mono3<<<NBLK, 256, 0, stream>>>(
            fea0, fea1, fea2, fea3, W_mu, b_mu, W_var, b_var,
            (u64*)d_ws, out);
    } else {
        float* ws = (float*)d_ws;
        const int nblk = NSAMP / 4;
        ib_fused<<<dim3(nblk, NLAYER), 256, 0, stream>>>(
            fea0, fea1, fea2, fea3, W_mu, b_mu, W_var, b_var, ws);
        ib_final<<<1, 256, 0, stream>>>(ws, nblk * NLAYER,
                                        1.0f / (float)NSAMP, out);
    }
}

// Round 13
// 28.549 us; speedup vs baseline: 1.4516x; 1.4516x over previous
//
#include <hip/hip_runtime.h>
#include <math.h>

#define NSAMP 1024
#define DIM   64
#define NLAYER 3

#define NT3 32                         // rows per pair block
#define JG  128                        // j per pair block
#define CH3 64                         // j per LDS chunk (2 chunks/block)
#define NBLK (NLAYER * (NSAMP/NT3) * (NSAMP/JG))   // 3*32*8 = 768

#define MAGIC_HI 0x5AFE600Du

// workspace layout (float units)
#define MU_OFF   0
#define INV_OFF  (NLAYER * NSAMP * DIM)        // 196608
#define SLOT_F   (2 * NLAYER * NSAMP * DIM)    // 393216 (8B aligned)
#define WS_REQ   ((size_t)SLOT_F * sizeof(float) + NBLK * sizeof(unsigned long long))

typedef unsigned long long u64;

// 2-instr |f-mu| accumulate (proven R11): v_sub + v_add with abs() modifier.
__device__ __forceinline__ void absacc(float& acc, float f, float m) {
    float d;
    asm("v_sub_f32 %1, %2, %3\n\t"
        "v_add_f32 %0, %0, abs(%1)"
        : "+v"(acc), "=&v"(d)
        : "v"(f), "v"(m));
}

// ---------------------------------------------------------------------------
// Dispatch 1: head precompute (proven, verbatim since R6).
__global__ __launch_bounds__(256) void ib_head(
    const float* __restrict__ f1, const float* __restrict__ f2,
    const float* __restrict__ f3,
    const float* __restrict__ W_mu, const float* __restrict__ b_mu,
    const float* __restrict__ W_var, const float* __restrict__ b_var,
    float* __restrict__ ws)
{
    const int layer = blockIdx.y;
    const float* __restrict__ fs_p = (layer == 0) ? f1 : (layer == 1) ? f2 : f3;

    const int tid = threadIdx.x;
    const int d   = tid & 63;
    const int nl  = tid >> 6;
    const int n   = blockIdx.x * 4 + nl;

    __shared__ float fs[4][DIM];
    fs[nl][d] = fs_p[n * DIM + d];
    __syncthreads();

    const float4* __restrict__ wm = (const float4*)(W_mu + (layer * DIM + d) * DIM);
    const float4* __restrict__ wv = (const float4*)(W_var + (layer * DIM + d) * DIM);
    float am = 0.f, av = 0.f;
#pragma unroll
    for (int k = 0; k < DIM / 4; ++k) {
        const float4 m4 = wm[k];
        const float4 v4 = wv[k];
        const float f0 = fs[nl][k * 4 + 0];
        const float f1v = fs[nl][k * 4 + 1];
        const float f2v = fs[nl][k * 4 + 2];
        const float f3v = fs[nl][k * 4 + 3];
        am = fmaf(f0, m4.x, am); am = fmaf(f1v, m4.y, am);
        am = fmaf(f2v, m4.z, am); am = fmaf(f3v, m4.w, am);
        av = fmaf(f0, v4.x, av); av = fmaf(f1v, v4.y, av);
        av = fmaf(f2v, v4.z, av); av = fmaf(f3v, v4.w, av);
    }
    const float mu = am + b_mu[layer * DIM + d];
    const float x  = av + b_var[layer * DIM + d];
    const float sp  = fmaxf(x, 0.f) + log1pf(expf(-fabsf(x)));
    const float var = sp * 0.1f + 1e-6f;

    const int o = (layer * NSAMP + n) * DIM + d;
    ws[MU_OFF + o]  = mu;
    ws[INV_OFF + o] = 1.0f / var;
}

// ---------------------------------------------------------------------------
// Dispatch 2: pipelined pair kernel.
// Block = (layer, ntile[32 rows], jg[128 j]); thread = 4 rows x 4 cols,
// 64 j-iters (jsub splits each 64-j chunk in half). Two LDS chunks,
// double-buffered with async-stage split: chunk1's global loads are issued
// BEFORE chunk0's compute (latency hidden under ~2300 cyc of VALU), written
// to LDS after. One prologue/epilogue per 128 j instead of per 64.
// Finish: proven MAGIC-slot scheme.
__global__ __launch_bounds__(256, 4) void ib_pairp(
    const float* __restrict__ fea0, const float* __restrict__ fea1,
    const float* __restrict__ fea2,
    const float* __restrict__ ws, u64* __restrict__ slots,
    float* __restrict__ out)
{
    const int b     = blockIdx.x;          // 0..767
    const int layer = b >> 8;              // 256 blocks per layer
    const int sub   = b & 255;
    const int ntile = sub & 31;            // 0..31 (32-row tiles)
    const int jg    = sub >> 5;            // 0..7  (128-j groups)
    const int tid   = threadIdx.x;

    const float* __restrict__ fr_p =
        (layer == 0) ? fea0 : (layer == 1) ? fea1 : fea2;

    const int q    = tid & 15;             // 4 cols
    const int rg   = (tid >> 4) & 7;       // 4 rows
    const int jsub = tid >> 7;             // 0/1: 32-j half of each chunk
    const int d0   = q * 4;
    const int n0   = ntile * NT3 + rg * 4;

    __shared__ float4 buf[2][CH3][DIM / 4];   // 32 KB
    __shared__ float  wsum[4];

    // mu for my 4 rows (written by previous dispatch; L2-resident)
    const float4* __restrict__ mup =
        (const float4*)(ws + MU_OFF + (layer * NSAMP + n0) * DIM + d0);
    float4 mu4[4];
#pragma unroll
    for (int r = 0; r < 4; ++r) mu4[r] = mup[r * (DIM / 4)];

    // stage chunk 0 (64 rows x 64 floats, coalesced float4)
    const float4* __restrict__ src0 = (const float4*)(fr_p + (jg * JG) * DIM);
#pragma unroll
    for (int t = 0; t < 4; ++t)
        ((float4*)buf)[tid + 256 * t] = src0[tid + 256 * t];
    __syncthreads();

    // issue chunk-1 loads NOW (in flight during chunk-0 compute)
    const float4* __restrict__ src1 = src0 + CH3 * (DIM / 4);
    float4 g[4];
#pragma unroll
    for (int t = 0; t < 4; ++t)
        g[t] = src1[tid + 256 * t];

    float4 ps[4];
#pragma unroll
    for (int r = 0; r < 4; ++r) ps[r] = make_float4(0.f, 0.f, 0.f, 0.f);

    const int jb = jsub * 32;

    // compute chunk 0
#pragma unroll 4
    for (int jj = 0; jj < 32; ++jj) {
        const float4 f = buf[0][jb + jj][q];
#pragma unroll
        for (int r = 0; r < 4; ++r) {
            absacc(ps[r].x, f.x, mu4[r].x);
            absacc(ps[r].y, f.y, mu4[r].y);
            absacc(ps[r].z, f.z, mu4[r].z);
            absacc(ps[r].w, f.w, mu4[r].w);
        }
    }

    // write chunk 1 to LDS (loads have had ~2300 cyc to land), publish
#pragma unroll
    for (int t = 0; t < 4; ++t)
        ((float4*)buf)[1024 + tid + 256 * t] = g[t];
    __syncthreads();

    // compute chunk 1
#pragma unroll 4
    for (int jj = 0; jj < 32; ++jj) {
        const float4 f = buf[1][jb + jj][q];
#pragma unroll
        for (int r = 0; r < 4; ++r) {
            absacc(ps[r].x, f.x, mu4[r].x);
            absacc(ps[r].y, f.y, mu4[r].y);
            absacc(ps[r].z, f.z, mu4[r].z);
            absacc(ps[r].w, f.w, mu4[r].w);
        }
    }

    // ---------------- epilogue ----------------------------------------------
    const float4* __restrict__ ivp =
        (const float4*)(ws + INV_OFF + (layer * NSAMP + n0) * DIM + d0);
    const float inv_n = 1.0f / (float)NSAMP;
    float s = 0.f;
    if (jg == 0 && jsub == 0) {
        // positive term exactly once per (n,d)
        const float4* __restrict__ fsp = (const float4*)(fr_p + n0 * DIM + d0);
#pragma unroll
        for (int r = 0; r < 4; ++r) {
            const float4 iv = ivp[r * (DIM / 4)];
            const float4 a  = fsp[r * (DIM / 4)];
            s += (ps[r].x * inv_n - fabsf(mu4[r].x - a.x)) * iv.x;
            s += (ps[r].y * inv_n - fabsf(mu4[r].y - a.y)) * iv.y;
            s += (ps[r].z * inv_n - fabsf(mu4[r].z - a.z)) * iv.z;
            s += (ps[r].w * inv_n - fabsf(mu4[r].w - a.w)) * iv.w;
        }
    } else {
#pragma unroll
        for (int r = 0; r < 4; ++r) {
            const float4 iv = ivp[r * (DIM / 4)];
            s += ps[r].x * inv_n * iv.x;
            s += ps[r].y * inv_n * iv.y;
            s += ps[r].z * inv_n * iv.z;
            s += ps[r].w * inv_n * iv.w;
        }
    }

    // deterministic block reduction
#pragma unroll
    for (int off = 32; off > 0; off >>= 1)
        s += __shfl_down(s, off, 64);
    if ((tid & 63) == 0) wsum[tid >> 6] = s;
    __syncthreads();

    // one contention-free 8B MAGIC store per block (own slot)
    if (tid == 0) {
        const float p = wsum[0] + wsum[1] + wsum[2] + wsum[3];
        const u64 v = ((u64)MAGIC_HI << 32) | (u64)__float_as_uint(p);
        __hip_atomic_store(&slots[b], v, __ATOMIC_RELAXED,
                           __HIP_MEMORY_SCOPE_AGENT);
    }

    // block 0: completion-only wait (safe, proven), fixed-order reduce, reset
    if (b == 0) {
        __syncthreads();
        u64 v[3];
#pragma unroll
        for (int t = 0; t < 3; ++t) {
            u64* slot = &slots[tid + t * 256];
            for (;;) {
                const u64 x = __hip_atomic_load(slot, __ATOMIC_RELAXED,
                                                __HIP_MEMORY_SCOPE_AGENT);
                if ((unsigned)(x >> 32) == MAGIC_HI) { v[t] = x; break; }
                __builtin_amdgcn_s_sleep(1);
            }
        }
#pragma unroll
        for (int t = 0; t < 3; ++t)
            __hip_atomic_store(&slots[tid + t * 256], 0ull, __ATOMIC_RELAXED,
                               __HIP_MEMORY_SCOPE_AGENT);
        float s2 = __uint_as_float((unsigned)v[0])
                 + __uint_as_float((unsigned)v[1])
                 + __uint_as_float((unsigned)v[2]);
#pragma unroll
        for (int off = 32; off > 0; off >>= 1)
            s2 += __shfl_down(s2, off, 64);
        if ((tid & 63) == 0) wsum[tid >> 6] = s2;
        __syncthreads();
        if (tid == 0)
            out[0] = (wsum[0] + wsum[1] + wsum[2] + wsum[3]) * inv_n;
    }
}

// ---------------------------------------------------------------------------
// fallback path (tiny ws): fused kernel + final reduce
__global__ __launch_bounds__(256) void ib_fused(
    const float* __restrict__ fea0, const float* __restrict__ fea1,
    const float* __restrict__ fea2, const float* __restrict__ fea3,
    const float* __restrict__ W_mu, const float* __restrict__ b_mu,
    const float* __restrict__ W_var, const float* __restrict__ b_var,
    float* __restrict__ partials)
{
    const int layer = blockIdx.y;
    const float* feas[4] = {fea0, fea1, fea2, fea3};
    const float* __restrict__ fr_p = feas[layer];
    const float* __restrict__ fs_p = feas[layer + 1];

    const int tid = threadIdx.x;
    const int d   = tid & 63;
    const int nl  = tid >> 6;
    const int n   = blockIdx.x * 4 + nl;

    __shared__ float fs[4][DIM];
    __shared__ float fr[64][DIM];
    __shared__ float wsum[4];

    fs[nl][d] = fs_p[n * DIM + d];
    __syncthreads();

    const float* __restrict__ wm = W_mu + (layer * DIM + d) * DIM;
    const float* __restrict__ wv = W_var + (layer * DIM + d) * DIM;
    float am = 0.f, av = 0.f;
#pragma unroll
    for (int k = 0; k < DIM; ++k) {
        const float f = fs[nl][k];
        am = fmaf(f, wm[k], am);
        av = fmaf(f, wv[k], av);
    }
    const float mu = am + b_mu[layer * DIM + d];
    const float x  = av + b_var[layer * DIM + d];
    const float sp  = fmaxf(x, 0.f) + log1pf(expf(-fabsf(x)));
    const float var = sp * 0.1f + 1e-6f;

    float psum = 0.f;
    for (int j0 = 0; j0 < NSAMP; j0 += 64) {
        __syncthreads();
#pragma unroll
        for (int t = 0; t < 16; ++t) {
            const int l = tid + t * 256;
            fr[0][l] = fr_p[j0 * DIM + l];
        }
        __syncthreads();
#pragma unroll
        for (int j = 0; j < 64; ++j)
            psum += fabsf(fr[j][d] - mu);
    }

    const float frnd = fr_p[n * DIM + d];
    float t = (psum * (1.0f / NSAMP) - fabsf(mu - frnd)) / var;

#pragma unroll
    for (int off = 32; off > 0; off >>= 1)
        t += __shfl_down(t, off, 64);
    if ((tid & 63) == 0) wsum[tid >> 6] = t;
    __syncthreads();
    if (tid == 0)
        partials[blockIdx.y * gridDim.x + blockIdx.x] =
            wsum[0] + wsum[1] + wsum[2] + wsum[3];
}

__global__ __launch_bounds__(256) void ib_final(
    const float* __restrict__ partials, int np, float scale,
    float* __restrict__ out)
{
    const int tid = threadIdx.x;
    float s = 0.f;
    for (int i = tid; i < np; i += 256) s += partials[i];
#pragma unroll
    for (int off = 32; off > 0; off >>= 1)
        s += __shfl_down(s, off, 64);
    __shared__ float wsum[4];
    if ((tid & 63) == 0) wsum[tid >> 6] = s;
    __syncthreads();
    if (tid == 0) out[0] = (wsum[0] + wsum[1] + wsum[2] + wsum[3]) * scale;
}

// ---------------------------------------------------------------------------
extern "C" void kernel_launch(void* const* d_in, const int* in_sizes, int n_in,
                              void* d_out, int out_size, void* d_ws, size_t ws_size,
                              hipStream_t stream) {
    const float* fea0  = (const float*)d_in[0];
    const float* fea1  = (const float*)d_in[1];
    const float* fea2  = (const float*)d_in[2];
    const float* fea3  = (const float*)d_in[3];
    const float* W_mu  = (const float*)d_in[4];
    const float* b_mu  = (const float*)d_in[5];
    const float* W_var = (const float*)d_in[6];
    const float* b_var = (const float*)d_in[7];
    float* out = (float*)d_out;
    float* ws  = (float*)d_ws;

    if (ws_size >= WS_REQ) {
        ib_head<<<dim3(NSAMP / 4, NLAYER), 256, 0, stream>>>(
            fea1, fea2, fea3, W_mu, b_mu, W_var, b_var, ws);
        ib_pairp<<<NBLK, 256, 0, stream>>>(
            fea0, fea1, fea2, ws, (u64*)(ws + SLOT_F), out);
    } else {
        const int nblk = NSAMP / 4;
        ib_fused<<<dim3(nblk, NLAYER), 256, 0, stream>>>(
            fea0, fea1, fea2, fea3, W_mu, b_mu, W_var, b_var, ws);
        ib_final<<<1, 256, 0, stream>>>(ws, nblk * NLAYER,
                                        1.0f / (float)NSAMP, out);
    }
}